// Round 6
// baseline (573.154 us; speedup 1.0000x reference)
//
#include <hip/hip_runtime.h>
#include <hip/hip_bf16.h>

typedef short short8 __attribute__((ext_vector_type(8)));
typedef unsigned short u16x8 __attribute__((ext_vector_type(8)));
typedef float f32x4 __attribute__((ext_vector_type(4)));

#define AS1 __attribute__((address_space(1)))
#define AS3 __attribute__((address_space(3)))

__device__ __forceinline__ void gload16(const void* g, void* l) {
  __builtin_amdgcn_global_load_lds((AS1 void*)g, (AS3 void*)l, 16, 0, 0);
}

__device__ __forceinline__ unsigned short f2bf(float f) {
  unsigned u = __float_as_uint(f);
  u = (u + 0x7FFF + ((u >> 16) & 1)) >> 16;  // RNE
  return (unsigned short)u;
}
__device__ __forceinline__ float bf2f(unsigned short u) {
  return __uint_as_float(((unsigned)u) << 16);
}

// ---------------- W transpose+convert: W [512][512] (k,n) -> Wt bf16 [n][k] ----------------
__global__ void cvt_wt_kernel(const float* __restrict__ W, unsigned short* __restrict__ Wt) {
  int idx = blockIdx.x * 256 + threadIdx.x;
  if (idx >= 512 * 512) return;
  int k = idx >> 9, n = idx & 511;
  Wt[n * 512 + k] = f2bf(W[idx]);
}

// ---------------- edge dtype detector ----------------
__global__ void detect64_kernel(const int* __restrict__ ei32, int* __restrict__ flag) {
  if (blockIdx.x == 0 && threadIdx.x == 0) {
    int f = 1;
    for (int i = 0; i < 64; ++i)
      if (ei32[2 * i + 1] != 0) { f = 0; break; }
    *flag = f;
  }
}

// ---------------- CSR build ----------------
__global__ void count_kernel(const int* __restrict__ ei32, const int* __restrict__ flag,
                             int* __restrict__ cnt, int E) {
  int e = blockIdx.x * 256 + threadIdx.x;
  if (e >= E) return;
  int c = (*flag) ? ei32[2 * E + 2 * e] : ei32[E + e];
  atomicAdd(&cnt[c], 1);
}

__global__ void __launch_bounds__(1024) scan_bsum_kernel(const int* __restrict__ cnt,
                                                         int* __restrict__ bsum, int n) {
  __shared__ int ws[16];
  const int tid = threadIdx.x, lane = tid & 63, wid = tid >> 6;
  const int i = blockIdx.x * 1024 + tid;
  int x = (i < n) ? cnt[i] : 0;
#pragma unroll
  for (int d = 1; d < 64; d <<= 1) x += __shfl_xor(x, d, 64);
  if (lane == 0) ws[wid] = x;
  __syncthreads();
  if (tid == 0) {
    int s = 0;
#pragma unroll
    for (int w = 0; w < 16; ++w) s += ws[w];
    bsum[blockIdx.x] = s;
  }
}

__global__ void scan_boff_kernel(int* __restrict__ bsum, int* __restrict__ total, int B) {
  const int lane = threadIdx.x;
  const int v = (lane < B) ? bsum[lane] : 0;
  int x = v;
#pragma unroll
  for (int d = 1; d < 64; d <<= 1) {
    int y = __shfl_up(x, d, 64);
    if (lane >= d) x += y;
  }
  if (lane < B) bsum[lane] = x - v;
  if (lane == B - 1) *total = x;
}

__global__ void __launch_bounds__(1024) scan_fill_kernel(const int* __restrict__ cnt,
    const int* __restrict__ boff, int* __restrict__ ptr, int* __restrict__ cur,
    float* __restrict__ dis, int n) {
  __shared__ int ws[16];
  const int tid = threadIdx.x, lane = tid & 63, wid = tid >> 6;
  const int i = blockIdx.x * 1024 + tid;
  const int v = (i < n) ? cnt[i] : 0;
  int x = v;
#pragma unroll
  for (int d = 1; d < 64; d <<= 1) {
    int y = __shfl_up(x, d, 64);
    if (lane >= d) x += y;
  }
  if (lane == 63) ws[wid] = x;
  __syncthreads();
  if (tid < 16) {
    int wv = ws[tid];
    int wx = wv;
#pragma unroll
    for (int d = 1; d < 16; d <<= 1) {
      int y = __shfl_up(wx, d, 64);
      if (tid >= d) wx += y;
    }
    ws[tid] = wx - wv;
  }
  __syncthreads();
  if (i < n) {
    const int excl = boff[blockIdx.x] + ws[wid] + (x - v);
    ptr[i] = excl;
    cur[i] = excl;
    dis[i] = rsqrtf((float)(v + 1));  // +1 self-loop
  }
}

__global__ void fill_kernel(const int* __restrict__ ei32, const int* __restrict__ flag,
                            int* __restrict__ cur, int* __restrict__ eidx, int E) {
  int e = blockIdx.x * 256 + threadIdx.x;
  if (e >= E) return;
  int is64 = *flag;
  int r = is64 ? ei32[2 * e] : ei32[e];
  int c = is64 ? ei32[2 * E + 2 * e] : ei32[E + e];
  int pos = atomicAdd(&cur[c], 1);
  eidx[pos] = r;
}

// ---------------- bf16 MFMA GEMM: C[M][512] = (A[M][512] @ Bt^T) * dscale[row] ----------------
template <bool F32A>
__global__ void __launch_bounds__(256) gemm_kernel(const void* __restrict__ Av,
                                                   const unsigned short* __restrict__ Bt,
                                                   const float* __restrict__ dscale,
                                                   unsigned short* __restrict__ C, int M) {
  __shared__ alignas(128) unsigned short As[2][8192];  // [buf][128 rows][64 k], slot-swizzled
  __shared__ alignas(128) unsigned short Bs[2][8192];
  const int tid = threadIdx.x;
  const int wave = tid >> 6, lane = tid & 63;
  const int wm = wave >> 1, wn = wave & 1;

  const int nbm = (M + 127) >> 7;
  const int nwg = nbm * 4;
  const int orig = blockIdx.x;
  const int xcd = orig & 7;
  const int q8 = nwg >> 3, r8 = nwg & 7;
  const int wg = (xcd < r8 ? xcd * (q8 + 1) : r8 * (q8 + 1) + (xcd - r8) * q8) + (orig >> 3);
  const int bn = wg & 3;
  const int bm = wg >> 2;

  const int lr = lane >> 3, ls = lane & 7;
  const int fr = lane & 15, ks = lane >> 4;

  const unsigned short* Ab = (const unsigned short*)Av;
  const float* Af = (const float*)Av;

  f32x4 acc[4][4] = {};

#define STAGE_B(BUF, KO)                                                                   \
  {                                                                                        \
    _Pragma("unroll") for (int i = 0; i < 4; ++i) {                                        \
      const int rb = bn * 128 + i * 32 + wave * 8 + lr;                                    \
      gload16(Bt + (size_t)rb * 512 + (KO) + ((ls ^ (lr & 7)) << 3),                       \
              &Bs[BUF][(i * 32 + wave * 8) * 64]);                                         \
    }                                                                                      \
  }
#define STAGE_A_BF(BUF, KO)                                                                \
  {                                                                                        \
    _Pragma("unroll") for (int i = 0; i < 4; ++i) {                                        \
      int ra = bm * 128 + i * 32 + wave * 8 + lr;                                          \
      ra = ra < M ? ra : M - 1;                                                            \
      gload16(Ab + (size_t)ra * 512 + (KO) + ((ls ^ (lr & 7)) << 3),                       \
              &As[BUF][(i * 32 + wave * 8) * 64]);                                         \
    }                                                                                      \
  }
#define STAGE_A_F32(BUF, KO)                                                               \
  {                                                                                        \
    _Pragma("unroll") for (int q = 0; q < 4; ++q) {                                        \
      const int task = q * 256 + tid;                                                      \
      const int r = task >> 3, sl = task & 7;                                              \
      int rg = bm * 128 + r;                                                               \
      rg = rg < M ? rg : M - 1;                                                            \
      const float* src = Af + (size_t)rg * 512 + (KO) + sl * 8;                            \
      const float4 a0 = *(const float4*)src;                                               \
      const float4 a1 = *(const float4*)(src + 4);                                         \
      u16x8 o;                                                                             \
      o[0] = __bfloat16_as_ushort(__float2bfloat16(a0.x));                                 \
      o[1] = __bfloat16_as_ushort(__float2bfloat16(a0.y));                                 \
      o[2] = __bfloat16_as_ushort(__float2bfloat16(a0.z));                                 \
      o[3] = __bfloat16_as_ushort(__float2bfloat16(a0.w));                                 \
      o[4] = __bfloat16_as_ushort(__float2bfloat16(a1.x));                                 \
      o[5] = __bfloat16_as_ushort(__float2bfloat16(a1.y));                                 \
      o[6] = __bfloat16_as_ushort(__float2bfloat16(a1.z));                                 \
      o[7] = __bfloat16_as_ushort(__float2bfloat16(a1.w));                                 \
      *(u16x8*)&As[BUF][r * 64 + ((sl ^ (r & 7)) << 3)] = o;                               \
    }                                                                                      \
  }
#define STAGE(BUF, KO)                \
  {                                   \
    if (F32A) STAGE_A_F32(BUF, KO)    \
    else      STAGE_A_BF(BUF, KO)     \
    STAGE_B(BUF, KO)                  \
  }

  STAGE(0, 0)
  __syncthreads();

  int buf = 0;
  for (int kt = 0; kt < 8; ++kt) {
    if (kt < 7) STAGE(buf ^ 1, (kt + 1) * 64)

    short8 af[2][4], bfg[2][4];
#pragma unroll
    for (int m = 0; m < 4; ++m) {
      const int tr = wm * 64 + m * 16 + fr;
      af[0][m] = *(const short8*)&As[buf][tr * 64 + (((ks * 8)      ) ^ ((tr & 7) << 3))];
      af[1][m] = *(const short8*)&As[buf][tr * 64 + (((ks * 8) + 32 ) ^ ((tr & 7) << 3))];
    }
#pragma unroll
    for (int n = 0; n < 4; ++n) {
      const int tb = wn * 64 + n * 16 + fr;
      bfg[0][n] = *(const short8*)&Bs[buf][tb * 64 + (((ks * 8)      ) ^ ((tb & 7) << 3))];
      bfg[1][n] = *(const short8*)&Bs[buf][tb * 64 + (((ks * 8) + 32 ) ^ ((tb & 7) << 3))];
    }
#pragma unroll
    for (int kk = 0; kk < 2; ++kk)
#pragma unroll
      for (int m = 0; m < 4; ++m)
#pragma unroll
        for (int n = 0; n < 4; ++n)
          acc[m][n] = __builtin_amdgcn_mfma_f32_16x16x32_bf16(af[kk][m], bfg[kk][n], acc[m][n], 0, 0, 0);

    __syncthreads();
    buf ^= 1;
  }
#undef STAGE
#undef STAGE_A_F32
#undef STAGE_A_BF
#undef STAGE_B

  const int rbase = bm * 128 + wm * 64 + (lane >> 4) * 4;
  const int cbase = bn * 128 + wn * 64 + (lane & 15);
#pragma unroll
  for (int m = 0; m < 4; ++m)
#pragma unroll
    for (int j = 0; j < 4; ++j) {
      const int r = rbase + m * 16 + j;
      if (r < M) {
        const float ds = dscale[r];
#pragma unroll
        for (int n = 0; n < 4; ++n)
          C[(size_t)r * 512 + cbase + n * 16] = f2bf(acc[m][n][j] * ds);
      }
    }
}

// ---------------- aggregation: XCD-pinned 64-col slices, 8 edges x 8 lanes per wave ----------
// Block b: slice s = b&7 (cols 64s..64s+64; round-robin dispatch pins s to XCD s -> per-XCD
// h-footprint 6.4MB), node = (b>>3)*4 + wave. Lane = (es=lane>>3 edge slot, co=lane&7 16B chunk).
// h is dis-prescaled: out[i] = dis[i]*(sum_src h[src] + h[i]) + b.
template <bool FINAL>
__global__ void __launch_bounds__(256) agg_kernel(const unsigned short* __restrict__ h,
    const int* __restrict__ eidx, const int* __restrict__ ptr, const float* __restrict__ dis,
    const float* __restrict__ bias, void* __restrict__ outv, int n) {
  const int lane = threadIdx.x & 63;
  const int slice = blockIdx.x & 7;
  const int node = ((blockIdx.x >> 3) << 2) + (threadIdx.x >> 6);
  if (node >= n) return;
  const int es = lane >> 3;                 // edge sub-slot 0..7
  const int co = lane & 7;                  // 16B chunk 0..7
  const int fbase = slice * 64 + co * 8;    // 8 feature cols per lane

  float acc[8] = {0, 0, 0, 0, 0, 0, 0, 0};
  const int start = ptr[node], end = ptr[node + 1];

  for (int e = start + es; e < end; e += 8) {
    const int src = eidx[e];                // 8 lanes share src -> L1 broadcast
    const u16x8 v = *(const u16x8*)(h + (size_t)(unsigned)src * 512 + fbase);
#pragma unroll
    for (int j = 0; j < 8; ++j) acc[j] += bf2f(v[j]);
  }

  // reduce over edge sub-slots (lane bits 3..5)
#pragma unroll
  for (int d = 8; d <= 32; d <<= 1)
#pragma unroll
    for (int j = 0; j < 8; ++j) acc[j] += __shfl_xor(acc[j], d, 64);

  if (es == 0) {
    const u16x8 v = *(const u16x8*)(h + (size_t)node * 512 + fbase);  // self loop
    const float di = dis[node];
    float b[8];
    *(float4*)&b[0] = *(const float4*)(bias + fbase);
    *(float4*)&b[4] = *(const float4*)(bias + fbase + 4);
    if (FINAL) {
      float* out = (float*)outv;
      float4 o0, o1;
      o0.x = (acc[0] + bf2f(v[0])) * di + b[0];
      o0.y = (acc[1] + bf2f(v[1])) * di + b[1];
      o0.z = (acc[2] + bf2f(v[2])) * di + b[2];
      o0.w = (acc[3] + bf2f(v[3])) * di + b[3];
      o1.x = (acc[4] + bf2f(v[4])) * di + b[4];
      o1.y = (acc[5] + bf2f(v[5])) * di + b[5];
      o1.z = (acc[6] + bf2f(v[6])) * di + b[6];
      o1.w = (acc[7] + bf2f(v[7])) * di + b[7];
      *(float4*)(out + (size_t)node * 512 + fbase) = o0;
      *(float4*)(out + (size_t)node * 512 + fbase + 4) = o1;
    } else {
      unsigned short* out = (unsigned short*)outv;
      u16x8 o;
#pragma unroll
      for (int j = 0; j < 8; ++j) {
        const float t = (acc[j] + bf2f(v[j])) * di + b[j];
        o[j] = f2bf(t > 0.0f ? t : 0.0f);
      }
      *(u16x8*)(out + (size_t)node * 512 + fbase) = o;
    }
  }
}

// ---------------- launch ----------------
extern "C" void kernel_launch(void* const* d_in, const int* in_sizes, int n_in,
                              void* d_out, int out_size, void* d_ws, size_t ws_size,
                              hipStream_t stream) {
  const float* x  = (const float*)d_in[0];
  const int*   ei = (const int*)d_in[1];
  const float* W1 = (const float*)d_in[2];
  const float* b1 = (const float*)d_in[3];
  const float* W2 = (const float*)d_in[4];
  const float* b2 = (const float*)d_in[5];
  float* out = (float*)d_out;

  const int M = in_sizes[0] / 512;  // 50000
  const int E = in_sizes[1] / 2;    // 800000

  auto alignup = [](size_t v) { return (v + 255) & ~(size_t)255; };
  char* p = (char*)d_ws;
  unsigned short* h1b = (unsigned short*)p; p += alignup((size_t)M * 512 * 2);
  unsigned short* r1b = (unsigned short*)p; p += alignup((size_t)M * 512 * 2);
  unsigned short* h2b = (unsigned short*)p; p += alignup((size_t)M * 512 * 2);
  unsigned short* w1b = (unsigned short*)p; p += alignup(512 * 512 * 2);
  unsigned short* w2b = (unsigned short*)p; p += alignup(512 * 512 * 2);
  float* dis = (float*)p; p += alignup((size_t)M * 4);
  int* ptr   = (int*)p;   p += alignup((size_t)(M + 1) * 4);
  int* cur   = (int*)p;   p += alignup((size_t)M * 4);
  int* eidx  = (int*)p;   p += alignup((size_t)E * 4);
  int* flag  = (int*)p;   p += alignup(256);
  int* bsum  = (int*)p;   p += alignup(1024);
  int* cnt = (int*)h1b;  // aliases h1b region (dead before GEMM1 writes h1b)

  hipMemsetAsync(cnt, 0, (size_t)M * 4, stream);
  detect64_kernel<<<1, 64, 0, stream>>>(ei, flag);

  cvt_wt_kernel<<<1024, 256, 0, stream>>>(W1, w1b);
  cvt_wt_kernel<<<1024, 256, 0, stream>>>(W2, w2b);

  const int B = (M + 1023) / 1024;
  count_kernel<<<(E + 255) / 256, 256, 0, stream>>>(ei, flag, cnt, E);
  scan_bsum_kernel<<<B, 1024, 0, stream>>>(cnt, bsum, M);
  scan_boff_kernel<<<1, 64, 0, stream>>>(bsum, ptr + M, B);
  scan_fill_kernel<<<B, 1024, 0, stream>>>(cnt, bsum, ptr, cur, dis, M);
  fill_kernel<<<(E + 255) / 256, 256, 0, stream>>>(ei, flag, cur, eidx, E);

  const int nwg = ((M + 127) / 128) * 4;
  const int nag = ((M + 3) / 4) * 8;
  gemm_kernel<true><<<nwg, 256, 0, stream>>>((const void*)x, w1b, dis, h1b, M);
  agg_kernel<false><<<nag, 256, 0, stream>>>(h1b, eidx, ptr, dis, b1, (void*)r1b, M);
  gemm_kernel<false><<<nwg, 256, 0, stream>>>((const void*)r1b, w2b, dis, h2b, M);
  agg_kernel<true><<<nag, 256, 0, stream>>>(h2b, eidx, ptr, dis, b2, (void*)out, M);
}

// Round 7
// 485.148 us; speedup vs baseline: 1.1814x; 1.1814x over previous
//
#include <hip/hip_runtime.h>
#include <hip/hip_bf16.h>

typedef short short8 __attribute__((ext_vector_type(8)));
typedef unsigned short u16x8 __attribute__((ext_vector_type(8)));
typedef float f32x4 __attribute__((ext_vector_type(4)));

#define AS1 __attribute__((address_space(1)))
#define AS3 __attribute__((address_space(3)))

__device__ __forceinline__ void gload16(const void* g, void* l) {
  __builtin_amdgcn_global_load_lds((AS1 void*)g, (AS3 void*)l, 16, 0, 0);
}

__device__ __forceinline__ unsigned short f2bf(float f) {
  unsigned u = __float_as_uint(f);
  u = (u + 0x7FFF + ((u >> 16) & 1)) >> 16;  // RNE
  return (unsigned short)u;
}
__device__ __forceinline__ float bf2f(unsigned short u) {
  return __uint_as_float(((unsigned)u) << 16);
}

// ---------------- prep: x f32->bf16 (vectorized) + W1/W2 transpose-convert ----------------
__global__ void prep_kernel(const float4* __restrict__ x4, ushort4* __restrict__ xb4, int n4,
                            const float* __restrict__ W1, unsigned short* __restrict__ W1t,
                            const float* __restrict__ W2, unsigned short* __restrict__ W2t) {
  const int nthr = gridDim.x * 256;
  for (int i = blockIdx.x * 256 + threadIdx.x; i < n4; i += nthr) {
    float4 v = x4[i];
    ushort4 o;
    o.x = f2bf(v.x); o.y = f2bf(v.y); o.z = f2bf(v.z); o.w = f2bf(v.w);
    xb4[i] = o;
  }
  for (int idx = blockIdx.x * 256 + threadIdx.x; idx < 512 * 512; idx += nthr) {
    const int k = idx >> 9, n = idx & 511;
    W1t[n * 512 + k] = f2bf(W1[idx]);
    W2t[n * 512 + k] = f2bf(W2[idx]);
  }
}

// ---------------- edge dtype detector ----------------
__global__ void detect64_kernel(const int* __restrict__ ei32, int* __restrict__ flag) {
  if (blockIdx.x == 0 && threadIdx.x == 0) {
    int f = 1;
    for (int i = 0; i < 64; ++i)
      if (ei32[2 * i + 1] != 0) { f = 0; break; }
    *flag = f;
  }
}

// ---------------- CSR build ----------------
__global__ void count_kernel(const int* __restrict__ ei32, const int* __restrict__ flag,
                             int* __restrict__ cnt, int E) {
  int e = blockIdx.x * 256 + threadIdx.x;
  if (e >= E) return;
  int c = (*flag) ? ei32[2 * E + 2 * e] : ei32[E + e];
  atomicAdd(&cnt[c], 1);
}

__global__ void __launch_bounds__(1024) scan_bsum_kernel(const int* __restrict__ cnt,
                                                         int* __restrict__ bsum, int n) {
  __shared__ int ws[16];
  const int tid = threadIdx.x, lane = tid & 63, wid = tid >> 6;
  const int i = blockIdx.x * 1024 + tid;
  int x = (i < n) ? cnt[i] : 0;
#pragma unroll
  for (int d = 1; d < 64; d <<= 1) x += __shfl_xor(x, d, 64);
  if (lane == 0) ws[wid] = x;
  __syncthreads();
  if (tid == 0) {
    int s = 0;
#pragma unroll
    for (int w = 0; w < 16; ++w) s += ws[w];
    bsum[blockIdx.x] = s;
  }
}

__global__ void scan_boff_kernel(int* __restrict__ bsum, int* __restrict__ total, int B) {
  const int lane = threadIdx.x;
  const int v = (lane < B) ? bsum[lane] : 0;
  int x = v;
#pragma unroll
  for (int d = 1; d < 64; d <<= 1) {
    int y = __shfl_up(x, d, 64);
    if (lane >= d) x += y;
  }
  if (lane < B) bsum[lane] = x - v;
  if (lane == B - 1) *total = x;
}

__global__ void __launch_bounds__(1024) scan_fill_kernel(const int* __restrict__ cnt,
    const int* __restrict__ boff, int* __restrict__ ptr, int* __restrict__ cur,
    float* __restrict__ dis, int n) {
  __shared__ int ws[16];
  const int tid = threadIdx.x, lane = tid & 63, wid = tid >> 6;
  const int i = blockIdx.x * 1024 + tid;
  const int v = (i < n) ? cnt[i] : 0;
  int x = v;
#pragma unroll
  for (int d = 1; d < 64; d <<= 1) {
    int y = __shfl_up(x, d, 64);
    if (lane >= d) x += y;
  }
  if (lane == 63) ws[wid] = x;
  __syncthreads();
  if (tid < 16) {
    int wv = ws[tid];
    int wx = wv;
#pragma unroll
    for (int d = 1; d < 16; d <<= 1) {
      int y = __shfl_up(wx, d, 64);
      if (tid >= d) wx += y;
    }
    ws[tid] = wx - wv;
  }
  __syncthreads();
  if (i < n) {
    const int excl = boff[blockIdx.x] + ws[wid] + (x - v);
    ptr[i] = excl;
    cur[i] = excl;
    dis[i] = rsqrtf((float)(v + 1));  // +1 self-loop
  }
}

__global__ void fill_kernel(const int* __restrict__ ei32, const int* __restrict__ flag,
                            int* __restrict__ cur, int* __restrict__ eidx, int E) {
  int e = blockIdx.x * 256 + threadIdx.x;
  if (e >= E) return;
  int is64 = *flag;
  int r = is64 ? ei32[2 * e] : ei32[e];
  int c = is64 ? ei32[2 * E + 2 * e] : ei32[E + e];
  int pos = atomicAdd(&cur[c], 1);
  eidx[pos] = r;
}

// ---------------- bf16 MFMA GEMM: C[M][512] = (A[M][512] @ Bt^T) * dscale[row] ----------------
// 128x128 tile, BK=64, double-buffered, conflict-free XOR slot-swizzle, XCD-chunk swizzle.
__global__ void __launch_bounds__(256) gemm_kernel(const unsigned short* __restrict__ A,
                                                   const unsigned short* __restrict__ Bt,
                                                   const float* __restrict__ dscale,
                                                   unsigned short* __restrict__ C, int M) {
  __shared__ alignas(128) unsigned short As[2][8192];  // [buf][128 rows][64 k], slot-swizzled
  __shared__ alignas(128) unsigned short Bs[2][8192];
  const int tid = threadIdx.x;
  const int wave = tid >> 6, lane = tid & 63;
  const int wm = wave >> 1, wn = wave & 1;

  // bijective XCD-chunk swizzle (m204), bn fastest so A-panel-sharing blocks are adjacent
  const int nbm = (M + 127) >> 7;
  const int nwg = nbm * 4;
  const int orig = blockIdx.x;
  const int xcd = orig & 7;
  const int q8 = nwg >> 3, r8 = nwg & 7;
  const int wg = (xcd < r8 ? xcd * (q8 + 1) : r8 * (q8 + 1) + (xcd - r8) * q8) + (orig >> 3);
  const int bn = wg & 3;
  const int bm = wg >> 2;

  const int lr = lane >> 3, ls = lane & 7;  // staging: row-in-8, 16B slot
  const int fr = lane & 15, ks = lane >> 4; // frag addressing

  f32x4 acc[4][4] = {};

  // linear LDS dest + inverse-swizzled global source slot (rule #21); read applies same XOR
#define STAGE(BUF, KO)                                                                     \
  {                                                                                        \
    _Pragma("unroll") for (int i = 0; i < 4; ++i) {                                        \
      int ra = bm * 128 + i * 32 + wave * 8 + lr;                                          \
      ra = ra < M ? ra : M - 1;                                                            \
      gload16(A + (size_t)ra * 512 + (KO) + ((ls ^ (lr & 7)) << 3),                        \
              &As[BUF][(i * 32 + wave * 8) * 64]);                                         \
      const int rb = bn * 128 + i * 32 + wave * 8 + lr;                                    \
      gload16(Bt + (size_t)rb * 512 + (KO) + ((ls ^ (lr & 7)) << 3),                       \
              &Bs[BUF][(i * 32 + wave * 8) * 64]);                                         \
    }                                                                                      \
  }

  STAGE(0, 0)
  __syncthreads();

  int buf = 0;
  for (int kt = 0; kt < 8; ++kt) {
    if (kt < 7) STAGE(buf ^ 1, (kt + 1) * 64)

    short8 af[2][4], bfg[2][4];
#pragma unroll
    for (int m = 0; m < 4; ++m) {
      const int tr = wm * 64 + m * 16 + fr;
      af[0][m] = *(const short8*)&As[buf][tr * 64 + (((ks * 8)      ) ^ ((tr & 7) << 3))];
      af[1][m] = *(const short8*)&As[buf][tr * 64 + (((ks * 8) + 32 ) ^ ((tr & 7) << 3))];
    }
#pragma unroll
    for (int n = 0; n < 4; ++n) {
      const int tb = wn * 64 + n * 16 + fr;
      bfg[0][n] = *(const short8*)&Bs[buf][tb * 64 + (((ks * 8)      ) ^ ((tb & 7) << 3))];
      bfg[1][n] = *(const short8*)&Bs[buf][tb * 64 + (((ks * 8) + 32 ) ^ ((tb & 7) << 3))];
    }
#pragma unroll
    for (int kk = 0; kk < 2; ++kk)
#pragma unroll
      for (int m = 0; m < 4; ++m)
#pragma unroll
        for (int n = 0; n < 4; ++n)
          acc[m][n] = __builtin_amdgcn_mfma_f32_16x16x32_bf16(af[kk][m], bfg[kk][n], acc[m][n], 0, 0, 0);

    __syncthreads();
    buf ^= 1;
  }
#undef STAGE

  // epilogue: D row=(lane>>4)*4+j, col=lane&15; prescale by dscale[row]
  const int rbase = bm * 128 + wm * 64 + (lane >> 4) * 4;
  const int cbase = bn * 128 + wn * 64 + (lane & 15);
#pragma unroll
  for (int m = 0; m < 4; ++m)
#pragma unroll
    for (int j = 0; j < 4; ++j) {
      const int r = rbase + m * 16 + j;
      if (r < M) {
        const float ds = dscale[r];
#pragma unroll
        for (int n = 0; n < 4; ++n)
          C[(size_t)r * 512 + cbase + n * 16] = f2bf(acc[m][n][j] * ds);
      }
    }
}

// ---------------- aggregation: one wave per node (R5 form — measured floor) ----------------
// h is dis-prescaled (GEMM epilogue). out[i] = dis[i]*(sum_nbr h[src] + h[i]) + b
template <bool FINAL>
__global__ void __launch_bounds__(256) agg_kernel(const unsigned short* __restrict__ h,
    const int* __restrict__ eidx, const int* __restrict__ ptr, const float* __restrict__ dis,
    const float* __restrict__ bias, void* __restrict__ outv, int n) {
  const int lane = threadIdx.x & 63;
  const int node = (blockIdx.x << 2) + (threadIdx.x >> 6);
  if (node >= n) return;
  const int fbase = lane << 3;  // 8 features per lane

  float acc[8];
  {  // self loop
    const u16x8 v = *(const u16x8*)(h + (size_t)node * 512 + fbase);
#pragma unroll
    for (int j = 0; j < 8; ++j) acc[j] = bf2f(v[j]);
  }

  const float di = dis[node];
  const int start = ptr[node], end = ptr[node + 1];

  int e = start;
  for (; e + 4 <= end; e += 4) {
    const int s0 = eidx[e], s1 = eidx[e + 1], s2 = eidx[e + 2], s3 = eidx[e + 3];
    const u16x8 v0 = *(const u16x8*)(h + (size_t)(unsigned)s0 * 512 + fbase);
    const u16x8 v1 = *(const u16x8*)(h + (size_t)(unsigned)s1 * 512 + fbase);
    const u16x8 v2 = *(const u16x8*)(h + (size_t)(unsigned)s2 * 512 + fbase);
    const u16x8 v3 = *(const u16x8*)(h + (size_t)(unsigned)s3 * 512 + fbase);
#pragma unroll
    for (int j = 0; j < 8; ++j)
      acc[j] += bf2f(v0[j]) + bf2f(v1[j]) + bf2f(v2[j]) + bf2f(v3[j]);
  }
  for (; e < end; ++e) {
    const int s0 = eidx[e];
    const u16x8 v = *(const u16x8*)(h + (size_t)(unsigned)s0 * 512 + fbase);
#pragma unroll
    for (int j = 0; j < 8; ++j) acc[j] += bf2f(v[j]);
  }

  float b[8];
  *(float4*)&b[0] = *(const float4*)(bias + fbase);
  *(float4*)&b[4] = *(const float4*)(bias + fbase + 4);

  if (FINAL) {
    float* out = (float*)outv;
    float4 o0, o1;
    o0.x = acc[0] * di + b[0]; o0.y = acc[1] * di + b[1];
    o0.z = acc[2] * di + b[2]; o0.w = acc[3] * di + b[3];
    o1.x = acc[4] * di + b[4]; o1.y = acc[5] * di + b[5];
    o1.z = acc[6] * di + b[6]; o1.w = acc[7] * di + b[7];
    *(float4*)(out + (size_t)node * 512 + fbase) = o0;
    *(float4*)(out + (size_t)node * 512 + fbase + 4) = o1;
  } else {
    unsigned short* out = (unsigned short*)outv;
    u16x8 o;
#pragma unroll
    for (int j = 0; j < 8; ++j) {
      float v = acc[j] * di + b[j];
      o[j] = f2bf(v > 0.0f ? v : 0.0f);
    }
    *(u16x8*)(out + (size_t)node * 512 + fbase) = o;
  }
}

// ---------------- launch ----------------
extern "C" void kernel_launch(void* const* d_in, const int* in_sizes, int n_in,
                              void* d_out, int out_size, void* d_ws, size_t ws_size,
                              hipStream_t stream) {
  const float* x  = (const float*)d_in[0];
  const int*   ei = (const int*)d_in[1];
  const float* W1 = (const float*)d_in[2];
  const float* b1 = (const float*)d_in[3];
  const float* W2 = (const float*)d_in[4];
  const float* b2 = (const float*)d_in[5];
  float* out = (float*)d_out;

  const int M = in_sizes[0] / 512;  // 50000
  const int E = in_sizes[1] / 2;    // 800000

  auto alignup = [](size_t v) { return (v + 255) & ~(size_t)255; };
  char* p = (char*)d_ws;
  unsigned short* xb  = (unsigned short*)p; p += alignup((size_t)M * 512 * 2);
  unsigned short* h1b = (unsigned short*)p; p += alignup((size_t)M * 512 * 2);
  unsigned short* r1b = (unsigned short*)p; p += alignup((size_t)M * 512 * 2);
  unsigned short* w1b = (unsigned short*)p; p += alignup(512 * 512 * 2);
  unsigned short* w2b = (unsigned short*)p; p += alignup(512 * 512 * 2);
  float* dis = (float*)p; p += alignup((size_t)M * 4);
  int* ptr   = (int*)p;   p += alignup((size_t)(M + 1) * 4);
  int* cur   = (int*)p;   p += alignup((size_t)M * 4);
  int* eidx  = (int*)p;   p += alignup((size_t)E * 4);
  int* flag  = (int*)p;   p += alignup(256);
  int* bsum  = (int*)p;   p += alignup(1024);
  int* cnt = (int*)h1b;      // aliases h1b region (dead before GEMM1 writes h1b)
  unsigned short* h2b = xb;  // xb dead after GEMM1

  hipMemsetAsync(cnt, 0, (size_t)M * 4, stream);
  detect64_kernel<<<1, 64, 0, stream>>>(ei, flag);

  prep_kernel<<<2048, 256, 0, stream>>>((const float4*)x, (ushort4*)xb, M * 128,
                                        W1, w1b, W2, w2b);

  const int B = (M + 1023) / 1024;
  count_kernel<<<(E + 255) / 256, 256, 0, stream>>>(ei, flag, cnt, E);
  scan_bsum_kernel<<<B, 1024, 0, stream>>>(cnt, bsum, M);
  scan_boff_kernel<<<1, 64, 0, stream>>>(bsum, ptr + M, B);
  scan_fill_kernel<<<B, 1024, 0, stream>>>(cnt, bsum, ptr, cur, dis, M);
  fill_kernel<<<(E + 255) / 256, 256, 0, stream>>>(ei, flag, cur, eidx, E);

  const int nwg = ((M + 127) / 128) * 4;
  gemm_kernel<<<nwg, 256, 0, stream>>>(xb, w1b, dis, h1b, M);
  agg_kernel<false><<<(M + 3) / 4, 256, 0, stream>>>(h1b, eidx, ptr, dis, b1, (void*)r1b, M);
  gemm_kernel<<<nwg, 256, 0, stream>>>(r1b, w2b, dis, h2b, M);
  agg_kernel<true><<<(M + 3) / 4, 256, 0, stream>>>(h2b, eidx, ptr, dis, b2, (void*)out, M);
}

// Round 8
// 427.104 us; speedup vs baseline: 1.3420x; 1.1359x over previous
//
#include <hip/hip_runtime.h>
#include <hip/hip_bf16.h>

typedef short short8 __attribute__((ext_vector_type(8)));
typedef unsigned short u16x8 __attribute__((ext_vector_type(8)));
typedef float f32x4 __attribute__((ext_vector_type(4)));

#define AS1 __attribute__((address_space(1)))
#define AS3 __attribute__((address_space(3)))

__device__ __forceinline__ void gload16(const void* g, void* l) {
  __builtin_amdgcn_global_load_lds((AS1 void*)g, (AS3 void*)l, 16, 0, 0);
}

__device__ __forceinline__ unsigned short f2bf(float f) {
  unsigned u = __float_as_uint(f);
  u = (u + 0x7FFF + ((u >> 16) & 1)) >> 16;  // RNE
  return (unsigned short)u;
}
__device__ __forceinline__ float bf2f(unsigned short u) {
  return __uint_as_float(((unsigned)u) << 16);
}

// ---------------- prep: x f32->bf16 (vectorized) + W1/W2 transpose-convert ----------------
__global__ void prep_kernel(const float4* __restrict__ x4, ushort4* __restrict__ xb4, int n4,
                            const float* __restrict__ W1, unsigned short* __restrict__ W1t,
                            const float* __restrict__ W2, unsigned short* __restrict__ W2t) {
  const int nthr = gridDim.x * 256;
  for (int i = blockIdx.x * 256 + threadIdx.x; i < n4; i += nthr) {
    float4 v = x4[i];
    ushort4 o;
    o.x = f2bf(v.x); o.y = f2bf(v.y); o.z = f2bf(v.z); o.w = f2bf(v.w);
    xb4[i] = o;
  }
  for (int idx = blockIdx.x * 256 + threadIdx.x; idx < 512 * 512; idx += nthr) {
    const int k = idx >> 9, n = idx & 511;
    W1t[n * 512 + k] = f2bf(W1[idx]);
    W2t[n * 512 + k] = f2bf(W2[idx]);
  }
}

// ---------------- edge dtype detector ----------------
__global__ void detect64_kernel(const int* __restrict__ ei32, int* __restrict__ flag) {
  if (blockIdx.x == 0 && threadIdx.x == 0) {
    int f = 1;
    for (int i = 0; i < 64; ++i)
      if (ei32[2 * i + 1] != 0) { f = 0; break; }
    *flag = f;
  }
}

// ---------------- CSR build ----------------
__global__ void count_kernel(const int* __restrict__ ei32, const int* __restrict__ flag,
                             int* __restrict__ cnt, int E) {
  int e = blockIdx.x * 256 + threadIdx.x;
  if (e >= E) return;
  int c = (*flag) ? ei32[2 * E + 2 * e] : ei32[E + e];
  atomicAdd(&cnt[c], 1);
}

__global__ void __launch_bounds__(1024) scan_bsum_kernel(const int* __restrict__ cnt,
                                                         int* __restrict__ bsum, int n) {
  __shared__ int ws[16];
  const int tid = threadIdx.x, lane = tid & 63, wid = tid >> 6;
  const int i = blockIdx.x * 1024 + tid;
  int x = (i < n) ? cnt[i] : 0;
#pragma unroll
  for (int d = 1; d < 64; d <<= 1) x += __shfl_xor(x, d, 64);
  if (lane == 0) ws[wid] = x;
  __syncthreads();
  if (tid == 0) {
    int s = 0;
#pragma unroll
    for (int w = 0; w < 16; ++w) s += ws[w];
    bsum[blockIdx.x] = s;
  }
}

__global__ void scan_boff_kernel(int* __restrict__ bsum, int* __restrict__ total, int B) {
  const int lane = threadIdx.x;
  const int v = (lane < B) ? bsum[lane] : 0;
  int x = v;
#pragma unroll
  for (int d = 1; d < 64; d <<= 1) {
    int y = __shfl_up(x, d, 64);
    if (lane >= d) x += y;
  }
  if (lane < B) bsum[lane] = x - v;
  if (lane == B - 1) *total = x;
}

__global__ void __launch_bounds__(1024) scan_fill_kernel(const int* __restrict__ cnt,
    const int* __restrict__ boff, int* __restrict__ ptr, int* __restrict__ cur,
    float* __restrict__ dis, int n) {
  __shared__ int ws[16];
  const int tid = threadIdx.x, lane = tid & 63, wid = tid >> 6;
  const int i = blockIdx.x * 1024 + tid;
  const int v = (i < n) ? cnt[i] : 0;
  int x = v;
#pragma unroll
  for (int d = 1; d < 64; d <<= 1) {
    int y = __shfl_up(x, d, 64);
    if (lane >= d) x += y;
  }
  if (lane == 63) ws[wid] = x;
  __syncthreads();
  if (tid < 16) {
    int wv = ws[tid];
    int wx = wv;
#pragma unroll
    for (int d = 1; d < 16; d <<= 1) {
      int y = __shfl_up(wx, d, 64);
      if (tid >= d) wx += y;
    }
    ws[tid] = wx - wv;
  }
  __syncthreads();
  if (i < n) {
    const int excl = boff[blockIdx.x] + ws[wid] + (x - v);
    ptr[i] = excl;
    cur[i] = excl;
    dis[i] = rsqrtf((float)(v + 1));  // +1 self-loop
  }
}

__global__ void fill_kernel(const int* __restrict__ ei32, const int* __restrict__ flag,
                            int* __restrict__ cur, int* __restrict__ eidx, int E) {
  int e = blockIdx.x * 256 + threadIdx.x;
  if (e >= E) return;
  int is64 = *flag;
  int r = is64 ? ei32[2 * e] : ei32[e];
  int c = is64 ? ei32[2 * E + 2 * e] : ei32[E + e];
  int pos = atomicAdd(&cur[c], 1);
  eidx[pos] = r;
}

// ---------------- bf16 MFMA GEMM: C[M][512] = (A[M][512] @ Bt^T) * dscale[row] ----------------
__global__ void __launch_bounds__(256) gemm_kernel(const unsigned short* __restrict__ A,
                                                   const unsigned short* __restrict__ Bt,
                                                   const float* __restrict__ dscale,
                                                   unsigned short* __restrict__ C, int M) {
  __shared__ alignas(128) unsigned short As[2][8192];  // [buf][128 rows][64 k], slot-swizzled
  __shared__ alignas(128) unsigned short Bs[2][8192];
  const int tid = threadIdx.x;
  const int wave = tid >> 6, lane = tid & 63;
  const int wm = wave >> 1, wn = wave & 1;

  const int nbm = (M + 127) >> 7;
  const int nwg = nbm * 4;
  const int orig = blockIdx.x;
  const int xcd = orig & 7;
  const int q8 = nwg >> 3, r8 = nwg & 7;
  const int wg = (xcd < r8 ? xcd * (q8 + 1) : r8 * (q8 + 1) + (xcd - r8) * q8) + (orig >> 3);
  const int bn = wg & 3;
  const int bm = wg >> 2;

  const int lr = lane >> 3, ls = lane & 7;
  const int fr = lane & 15, ks = lane >> 4;

  f32x4 acc[4][4] = {};

#define STAGE(BUF, KO)                                                                     \
  {                                                                                        \
    _Pragma("unroll") for (int i = 0; i < 4; ++i) {                                        \
      int ra = bm * 128 + i * 32 + wave * 8 + lr;                                          \
      ra = ra < M ? ra : M - 1;                                                            \
      gload16(A + (size_t)ra * 512 + (KO) + ((ls ^ (lr & 7)) << 3),                        \
              &As[BUF][(i * 32 + wave * 8) * 64]);                                         \
      const int rb = bn * 128 + i * 32 + wave * 8 + lr;                                    \
      gload16(Bt + (size_t)rb * 512 + (KO) + ((ls ^ (lr & 7)) << 3),                       \
              &Bs[BUF][(i * 32 + wave * 8) * 64]);                                         \
    }                                                                                      \
  }

  STAGE(0, 0)
  __syncthreads();

  int buf = 0;
  for (int kt = 0; kt < 8; ++kt) {
    if (kt < 7) STAGE(buf ^ 1, (kt + 1) * 64)

    short8 af[2][4], bfg[2][4];
#pragma unroll
    for (int m = 0; m < 4; ++m) {
      const int tr = wm * 64 + m * 16 + fr;
      af[0][m] = *(const short8*)&As[buf][tr * 64 + (((ks * 8)      ) ^ ((tr & 7) << 3))];
      af[1][m] = *(const short8*)&As[buf][tr * 64 + (((ks * 8) + 32 ) ^ ((tr & 7) << 3))];
    }
#pragma unroll
    for (int n = 0; n < 4; ++n) {
      const int tb = wn * 64 + n * 16 + fr;
      bfg[0][n] = *(const short8*)&Bs[buf][tb * 64 + (((ks * 8)      ) ^ ((tb & 7) << 3))];
      bfg[1][n] = *(const short8*)&Bs[buf][tb * 64 + (((ks * 8) + 32 ) ^ ((tb & 7) << 3))];
    }
#pragma unroll
    for (int kk = 0; kk < 2; ++kk)
#pragma unroll
      for (int m = 0; m < 4; ++m)
#pragma unroll
        for (int n = 0; n < 4; ++n)
          acc[m][n] = __builtin_amdgcn_mfma_f32_16x16x32_bf16(af[kk][m], bfg[kk][n], acc[m][n], 0, 0, 0);

    __syncthreads();
    buf ^= 1;
  }
#undef STAGE

  const int rbase = bm * 128 + wm * 64 + (lane >> 4) * 4;
  const int cbase = bn * 128 + wn * 64 + (lane & 15);
#pragma unroll
  for (int m = 0; m < 4; ++m)
#pragma unroll
    for (int j = 0; j < 4; ++j) {
      const int r = rbase + m * 16 + j;
      if (r < M) {
        const float ds = dscale[r];
#pragma unroll
        for (int n = 0; n < 4; ++n)
          C[(size_t)r * 512 + cbase + n * 16] = f2bf(acc[m][n][j] * ds);
      }
    }
}

// ---------------- aggregation: XCD-pinned slices, 8-lane group owns one node --------------
// Block b: slice = b&7 (cols 64*slice..+64) -> round-robin pins slice to XCD; per-XCD
// h-footprint = 50000*128B = 6.4MB. Group (8 lanes) owns node; edges sequential; per edge:
// broadcast eidx + one 16B/lane load (group reads the full 128B line) + 8 cvt-FMA.
// No cross-lane reduce. h is dis-prescaled: out[i] = dis[i]*(sum h[src] + h[i]) + b.
template <bool FINAL>
__global__ void __launch_bounds__(256) agg_kernel(const unsigned short* __restrict__ h,
    const int* __restrict__ eidx, const int* __restrict__ ptr, const float* __restrict__ dis,
    const float* __restrict__ bias, void* __restrict__ outv, int n) {
  const int tid = threadIdx.x;
  const int lane = tid & 63;
  const int slice = blockIdx.x & 7;
  const int g = lane >> 3;   // group 0..7 within wave
  const int c = lane & 7;    // 16B chunk 0..7 within group
  const int node = (int)(blockIdx.x >> 3) * 32 + (tid >> 6) * 8 + g;
  if (node >= n) return;
  const int fbase = slice * 64 + c * 8;  // 8 cols per lane

  const int start = ptr[node], end = ptr[node + 1];
  float acc[8] = {0, 0, 0, 0, 0, 0, 0, 0};

  int e = start;
  for (; e + 2 <= end; e += 2) {
    const int s0 = eidx[e], s1 = eidx[e + 1];  // 8 lanes same addr -> L1 broadcast
    const u16x8 v0 = *(const u16x8*)(h + (size_t)(unsigned)s0 * 512 + fbase);
    const u16x8 v1 = *(const u16x8*)(h + (size_t)(unsigned)s1 * 512 + fbase);
#pragma unroll
    for (int j = 0; j < 8; ++j) acc[j] += bf2f(v0[j]) + bf2f(v1[j]);
  }
  if (e < end) {
    const int s0 = eidx[e];
    const u16x8 v = *(const u16x8*)(h + (size_t)(unsigned)s0 * 512 + fbase);
#pragma unroll
    for (int j = 0; j < 8; ++j) acc[j] += bf2f(v[j]);
  }

  {  // self loop
    const u16x8 v = *(const u16x8*)(h + (size_t)node * 512 + fbase);
#pragma unroll
    for (int j = 0; j < 8; ++j) acc[j] += bf2f(v[j]);
  }

  const float di = dis[node];
  float b[8];
  *(float4*)&b[0] = *(const float4*)(bias + fbase);
  *(float4*)&b[4] = *(const float4*)(bias + fbase + 4);

  if (FINAL) {
    float* out = (float*)outv;
    float4 o0, o1;
    o0.x = acc[0] * di + b[0]; o0.y = acc[1] * di + b[1];
    o0.z = acc[2] * di + b[2]; o0.w = acc[3] * di + b[3];
    o1.x = acc[4] * di + b[4]; o1.y = acc[5] * di + b[5];
    o1.z = acc[6] * di + b[6]; o1.w = acc[7] * di + b[7];
    *(float4*)(out + (size_t)node * 512 + fbase) = o0;
    *(float4*)(out + (size_t)node * 512 + fbase + 4) = o1;
  } else {
    unsigned short* out = (unsigned short*)outv;
    u16x8 o;
#pragma unroll
    for (int j = 0; j < 8; ++j) {
      const float t = acc[j] * di + b[j];
      o[j] = f2bf(t > 0.0f ? t : 0.0f);
    }
    *(u16x8*)(out + (size_t)node * 512 + fbase) = o;
  }
}

// ---------------- launch ----------------
extern "C" void kernel_launch(void* const* d_in, const int* in_sizes, int n_in,
                              void* d_out, int out_size, void* d_ws, size_t ws_size,
                              hipStream_t stream) {
  const float* x  = (const float*)d_in[0];
  const int*   ei = (const int*)d_in[1];
  const float* W1 = (const float*)d_in[2];
  const float* b1 = (const float*)d_in[3];
  const float* W2 = (const float*)d_in[4];
  const float* b2 = (const float*)d_in[5];
  float* out = (float*)d_out;

  const int M = in_sizes[0] / 512;  // 50000
  const int E = in_sizes[1] / 2;    // 800000

  auto alignup = [](size_t v) { return (v + 255) & ~(size_t)255; };
  char* p = (char*)d_ws;
  unsigned short* xb  = (unsigned short*)p; p += alignup((size_t)M * 512 * 2);
  unsigned short* h1b = (unsigned short*)p; p += alignup((size_t)M * 512 * 2);
  unsigned short* r1b = (unsigned short*)p; p += alignup((size_t)M * 512 * 2);
  unsigned short* w1b = (unsigned short*)p; p += alignup(512 * 512 * 2);
  unsigned short* w2b = (unsigned short*)p; p += alignup(512 * 512 * 2);
  float* dis = (float*)p; p += alignup((size_t)M * 4);
  int* ptr   = (int*)p;   p += alignup((size_t)(M + 1) * 4);
  int* cur   = (int*)p;   p += alignup((size_t)M * 4);
  int* eidx  = (int*)p;   p += alignup((size_t)E * 4);
  int* flag  = (int*)p;   p += alignup(256);
  int* bsum  = (int*)p;   p += alignup(1024);
  int* cnt = (int*)h1b;      // aliases h1b region (dead before GEMM1 writes h1b)
  unsigned short* h2b = xb;  // xb dead after GEMM1

  hipMemsetAsync(cnt, 0, (size_t)M * 4, stream);
  detect64_kernel<<<1, 64, 0, stream>>>(ei, flag);

  prep_kernel<<<2048, 256, 0, stream>>>((const float4*)x, (ushort4*)xb, M * 128,
                                        W1, w1b, W2, w2b);

  const int B = (M + 1023) / 1024;
  count_kernel<<<(E + 255) / 256, 256, 0, stream>>>(ei, flag, cnt, E);
  scan_bsum_kernel<<<B, 1024, 0, stream>>>(cnt, bsum, M);
  scan_boff_kernel<<<1, 64, 0, stream>>>(bsum, ptr + M, B);
  scan_fill_kernel<<<B, 1024, 0, stream>>>(cnt, bsum, ptr, cur, dis, M);
  fill_kernel<<<(E + 255) / 256, 256, 0, stream>>>(ei, flag, cur, eidx, E);

  const int nwg = ((M + 127) / 128) * 4;
  const int nag = ((M + 31) / 32) * 8;
  gemm_kernel<<<nwg, 256, 0, stream>>>(xb, w1b, dis, h1b, M);
  agg_kernel<false><<<nag, 256, 0, stream>>>(h1b, eidx, ptr, dis, b1, (void*)r1b, M);
  gemm_kernel<<<nwg, 256, 0, stream>>>(r1b, w2b, dis, h2b, M);
  agg_kernel<true><<<nag, 256, 0, stream>>>(h2b, eidx, ptr, dis, b2, (void*)out, M);
}

// Round 9
// 410.931 us; speedup vs baseline: 1.3948x; 1.0394x over previous
//
#include <hip/hip_runtime.h>
#include <hip/hip_bf16.h>

typedef short short8 __attribute__((ext_vector_type(8)));
typedef unsigned short u16x8 __attribute__((ext_vector_type(8)));
typedef float f32x4 __attribute__((ext_vector_type(4)));

#define AS1 __attribute__((address_space(1)))
#define AS3 __attribute__((address_space(3)))

__device__ __forceinline__ void gload16(const void* g, void* l) {
  __builtin_amdgcn_global_load_lds((AS1 void*)g, (AS3 void*)l, 16, 0, 0);
}

__device__ __forceinline__ unsigned short f2bf(float f) {
  unsigned u = __float_as_uint(f);
  u = (u + 0x7FFF + ((u >> 16) & 1)) >> 16;  // RNE
  return (unsigned short)u;
}
__device__ __forceinline__ float bf2f(unsigned short u) {
  return __uint_as_float(((unsigned)u) << 16);
}

// ---------------- prep: x f32->bf16 (vectorized) + W1/W2 transpose-convert ----------------
__global__ void prep_kernel(const float4* __restrict__ x4, ushort4* __restrict__ xb4, int n4,
                            const float* __restrict__ W1, unsigned short* __restrict__ W1t,
                            const float* __restrict__ W2, unsigned short* __restrict__ W2t) {
  const int nthr = gridDim.x * 256;
  for (int i = blockIdx.x * 256 + threadIdx.x; i < n4; i += nthr) {
    float4 v = x4[i];
    ushort4 o;
    o.x = f2bf(v.x); o.y = f2bf(v.y); o.z = f2bf(v.z); o.w = f2bf(v.w);
    xb4[i] = o;
  }
  for (int idx = blockIdx.x * 256 + threadIdx.x; idx < 512 * 512; idx += nthr) {
    const int k = idx >> 9, n = idx & 511;
    W1t[n * 512 + k] = f2bf(W1[idx]);
    W2t[n * 512 + k] = f2bf(W2[idx]);
  }
}

// ---------------- edge dtype detector ----------------
__global__ void detect64_kernel(const int* __restrict__ ei32, int* __restrict__ flag) {
  if (blockIdx.x == 0 && threadIdx.x == 0) {
    int f = 1;
    for (int i = 0; i < 64; ++i)
      if (ei32[2 * i + 1] != 0) { f = 0; break; }
    *flag = f;
  }
}

// ---------------- CSR build ----------------
__global__ void count_kernel(const int* __restrict__ ei32, const int* __restrict__ flag,
                             int* __restrict__ cnt, int E) {
  int e = blockIdx.x * 256 + threadIdx.x;
  if (e >= E) return;
  int c = (*flag) ? ei32[2 * E + 2 * e] : ei32[E + e];
  atomicAdd(&cnt[c], 1);
}

__global__ void __launch_bounds__(1024) scan_bsum_kernel(const int* __restrict__ cnt,
                                                         int* __restrict__ bsum, int n) {
  __shared__ int ws[16];
  const int tid = threadIdx.x, lane = tid & 63, wid = tid >> 6;
  const int i = blockIdx.x * 1024 + tid;
  int x = (i < n) ? cnt[i] : 0;
#pragma unroll
  for (int d = 1; d < 64; d <<= 1) x += __shfl_xor(x, d, 64);
  if (lane == 0) ws[wid] = x;
  __syncthreads();
  if (tid == 0) {
    int s = 0;
#pragma unroll
    for (int w = 0; w < 16; ++w) s += ws[w];
    bsum[blockIdx.x] = s;
  }
}

__global__ void scan_boff_kernel(int* __restrict__ bsum, int* __restrict__ total, int B) {
  const int lane = threadIdx.x;
  const int v = (lane < B) ? bsum[lane] : 0;
  int x = v;
#pragma unroll
  for (int d = 1; d < 64; d <<= 1) {
    int y = __shfl_up(x, d, 64);
    if (lane >= d) x += y;
  }
  if (lane < B) bsum[lane] = x - v;
  if (lane == B - 1) *total = x;
}

__global__ void __launch_bounds__(1024) scan_fill_kernel(const int* __restrict__ cnt,
    const int* __restrict__ boff, int* __restrict__ ptr, int* __restrict__ cur,
    float* __restrict__ dis, int n) {
  __shared__ int ws[16];
  const int tid = threadIdx.x, lane = tid & 63, wid = tid >> 6;
  const int i = blockIdx.x * 1024 + tid;
  const int v = (i < n) ? cnt[i] : 0;
  int x = v;
#pragma unroll
  for (int d = 1; d < 64; d <<= 1) {
    int y = __shfl_up(x, d, 64);
    if (lane >= d) x += y;
  }
  if (lane == 63) ws[wid] = x;
  __syncthreads();
  if (tid < 16) {
    int wv = ws[tid];
    int wx = wv;
#pragma unroll
    for (int d = 1; d < 16; d <<= 1) {
      int y = __shfl_up(wx, d, 64);
      if (tid >= d) wx += y;
    }
    ws[tid] = wx - wv;
  }
  __syncthreads();
  if (i < n) {
    const int excl = boff[blockIdx.x] + ws[wid] + (x - v);
    ptr[i] = excl;
    cur[i] = excl;
    dis[i] = rsqrtf((float)(v + 1));  // +1 self-loop
  }
}

__global__ void fill_kernel(const int* __restrict__ ei32, const int* __restrict__ flag,
                            int* __restrict__ cur, int* __restrict__ eidx, int E) {
  int e = blockIdx.x * 256 + threadIdx.x;
  if (e >= E) return;
  int is64 = *flag;
  int r = is64 ? ei32[2 * e] : ei32[e];
  int c = is64 ? ei32[2 * E + 2 * e] : ei32[E + e];
  int pos = atomicAdd(&cur[c], 1);
  eidx[pos] = r;
}

// ---------------- bf16 MFMA GEMM: C = (A @ Bt^T) * dscale[row] ----------------
// 128x128 tile, BK=64, double-buffered, XOR slot-swizzle, XCD-chunk swizzle.
// BA: A stored column-blocked [512/64][M][64]; BC: C written column-blocked.
template <bool BA, bool BC>
__global__ void __launch_bounds__(256) gemm_kernel(const unsigned short* __restrict__ A,
                                                   const unsigned short* __restrict__ Bt,
                                                   const float* __restrict__ dscale,
                                                   unsigned short* __restrict__ C, int M) {
  __shared__ alignas(128) unsigned short As[2][8192];  // [buf][128 rows][64 k], slot-swizzled
  __shared__ alignas(128) unsigned short Bs[2][8192];
  const int tid = threadIdx.x;
  const int wave = tid >> 6, lane = tid & 63;
  const int wm = wave >> 1, wn = wave & 1;

  const int nbm = (M + 127) >> 7;
  const int nwg = nbm * 4;
  const int orig = blockIdx.x;
  const int xcd = orig & 7;
  const int q8 = nwg >> 3, r8 = nwg & 7;
  const int wg = (xcd < r8 ? xcd * (q8 + 1) : r8 * (q8 + 1) + (xcd - r8) * q8) + (orig >> 3);
  const int bn = wg & 3;
  const int bm = wg >> 2;

  const int lr = lane >> 3, ls = lane & 7;  // staging: row-in-8, 16B slot
  const int fr = lane & 15, ks = lane >> 4; // frag addressing

  f32x4 acc[4][4] = {};

  // linear LDS dest + inverse-swizzled global source slot (rule #21); read applies same XOR
#define STAGE(BUF, KO)                                                                     \
  {                                                                                        \
    _Pragma("unroll") for (int i = 0; i < 4; ++i) {                                        \
      int ra = bm * 128 + i * 32 + wave * 8 + lr;                                          \
      ra = ra < M ? ra : M - 1;                                                            \
      const size_t aoff = BA ? ((size_t)(KO)*M + (size_t)ra * 64 + ((ls ^ (lr & 7)) << 3)) \
                             : ((size_t)ra * 512 + (KO) + ((ls ^ (lr & 7)) << 3));         \
      gload16(A + aoff, &As[BUF][(i * 32 + wave * 8) * 64]);                               \
      const int rb = bn * 128 + i * 32 + wave * 8 + lr;                                    \
      gload16(Bt + (size_t)rb * 512 + (KO) + ((ls ^ (lr & 7)) << 3),                       \
              &Bs[BUF][(i * 32 + wave * 8) * 64]);                                         \
    }                                                                                      \
  }

  STAGE(0, 0)
  __syncthreads();

  int buf = 0;
  for (int kt = 0; kt < 8; ++kt) {
    if (kt < 7) STAGE(buf ^ 1, (kt + 1) * 64)

    short8 af[2][4], bfg[2][4];
#pragma unroll
    for (int m = 0; m < 4; ++m) {
      const int tr = wm * 64 + m * 16 + fr;
      af[0][m] = *(const short8*)&As[buf][tr * 64 + (((ks * 8)      ) ^ ((tr & 7) << 3))];
      af[1][m] = *(const short8*)&As[buf][tr * 64 + (((ks * 8) + 32 ) ^ ((tr & 7) << 3))];
    }
#pragma unroll
    for (int n = 0; n < 4; ++n) {
      const int tb = wn * 64 + n * 16 + fr;
      bfg[0][n] = *(const short8*)&Bs[buf][tb * 64 + (((ks * 8)      ) ^ ((tb & 7) << 3))];
      bfg[1][n] = *(const short8*)&Bs[buf][tb * 64 + (((ks * 8) + 32 ) ^ ((tb & 7) << 3))];
    }
#pragma unroll
    for (int kk = 0; kk < 2; ++kk)
#pragma unroll
      for (int m = 0; m < 4; ++m)
#pragma unroll
        for (int n = 0; n < 4; ++n)
          acc[m][n] = __builtin_amdgcn_mfma_f32_16x16x32_bf16(af[kk][m], bfg[kk][n], acc[m][n], 0, 0, 0);

    __syncthreads();
    buf ^= 1;
  }
#undef STAGE

  // epilogue: D row=(lane>>4)*4+j, col=lane&15; prescale by dscale[row]
  const int rbase = bm * 128 + wm * 64 + (lane >> 4) * 4;
  const int cbase = bn * 128 + wn * 64 + (lane & 15);
  const size_t hseg = (size_t)M * 64;
#pragma unroll
  for (int m = 0; m < 4; ++m)
#pragma unroll
    for (int j = 0; j < 4; ++j) {
      const int r = rbase + m * 16 + j;
      if (r < M) {
        const float ds = dscale[r];
#pragma unroll
        for (int n = 0; n < 4; ++n) {
          const unsigned short val = f2bf(acc[m][n][j] * ds);
          if (BC) {
            const int col = cbase + n * 16;
            C[(size_t)(col >> 6) * hseg + (size_t)r * 64 + (col & 63)] = val;
          } else {
            C[(size_t)r * 512 + cbase + n * 16] = val;
          }
        }
      }
    }
}

// ---------------- aggregation: XCD-pinned slices on column-blocked h --------------------
// h layout: [8 slices][M][64] — slice s contiguous 6.4MB, full L2 set coverage.
// Block b: slice = b&7 (round-robin pins slice to XCD). 8-lane group owns one node.
// h is dis-prescaled: out[i] = dis[i]*(sum h[src] + h[i]) + b.
template <bool FINAL>
__global__ void __launch_bounds__(256) agg_kernel(const unsigned short* __restrict__ h,
    const int* __restrict__ eidx, const int* __restrict__ ptr, const float* __restrict__ dis,
    const float* __restrict__ bias, void* __restrict__ outv, int n) {
  const int tid = threadIdx.x;
  const int lane = tid & 63;
  const int slice = blockIdx.x & 7;
  const int g = lane >> 3;   // group 0..7 within wave
  const int c = lane & 7;    // 16B chunk 0..7 within group
  const int node = (int)(blockIdx.x >> 3) * 32 + (tid >> 6) * 8 + g;
  if (node >= n) return;

  const unsigned short* hs = h + (size_t)slice * ((size_t)n * 64);  // slice region
  const int coff = c * 8;

  const int start = ptr[node], end = ptr[node + 1];
  float acc[8] = {0, 0, 0, 0, 0, 0, 0, 0};

  int e = start;
  for (; e + 2 <= end; e += 2) {
    const int s0 = eidx[e], s1 = eidx[e + 1];  // 8 lanes same addr -> L1 broadcast
    const u16x8 v0 = *(const u16x8*)(hs + (size_t)(unsigned)s0 * 64 + coff);
    const u16x8 v1 = *(const u16x8*)(hs + (size_t)(unsigned)s1 * 64 + coff);
#pragma unroll
    for (int j = 0; j < 8; ++j) acc[j] += bf2f(v0[j]) + bf2f(v1[j]);
  }
  if (e < end) {
    const int s0 = eidx[e];
    const u16x8 v = *(const u16x8*)(hs + (size_t)(unsigned)s0 * 64 + coff);
#pragma unroll
    for (int j = 0; j < 8; ++j) acc[j] += bf2f(v[j]);
  }

  {  // self loop
    const u16x8 v = *(const u16x8*)(hs + (size_t)node * 64 + coff);
#pragma unroll
    for (int j = 0; j < 8; ++j) acc[j] += bf2f(v[j]);
  }

  const float di = dis[node];
  const int fcol = slice * 64 + coff;
  float b[8];
  *(float4*)&b[0] = *(const float4*)(bias + fcol);
  *(float4*)&b[4] = *(const float4*)(bias + fcol + 4);

  if (FINAL) {
    float* out = (float*)outv;
    float4 o0, o1;
    o0.x = acc[0] * di + b[0]; o0.y = acc[1] * di + b[1];
    o0.z = acc[2] * di + b[2]; o0.w = acc[3] * di + b[3];
    o1.x = acc[4] * di + b[4]; o1.y = acc[5] * di + b[5];
    o1.z = acc[6] * di + b[6]; o1.w = acc[7] * di + b[7];
    *(float4*)(out + (size_t)node * 512 + fcol) = o0;
    *(float4*)(out + (size_t)node * 512 + fcol + 4) = o1;
  } else {  // write column-blocked bf16 (feeds GEMM2 as blocked-A)
    unsigned short* out = (unsigned short*)outv;
    u16x8 o;
#pragma unroll
    for (int j = 0; j < 8; ++j) {
      const float t = acc[j] * di + b[j];
      o[j] = f2bf(t > 0.0f ? t : 0.0f);
    }
    *(u16x8*)(out + (size_t)slice * ((size_t)n * 64) + (size_t)node * 64 + coff) = o;
  }
}

// ---------------- launch ----------------
extern "C" void kernel_launch(void* const* d_in, const int* in_sizes, int n_in,
                              void* d_out, int out_size, void* d_ws, size_t ws_size,
                              hipStream_t stream) {
  const float* x  = (const float*)d_in[0];
  const int*   ei = (const int*)d_in[1];
  const float* W1 = (const float*)d_in[2];
  const float* b1 = (const float*)d_in[3];
  const float* W2 = (const float*)d_in[4];
  const float* b2 = (const float*)d_in[5];
  float* out = (float*)d_out;

  const int M = in_sizes[0] / 512;  // 50000
  const int E = in_sizes[1] / 2;    // 800000

  auto alignup = [](size_t v) { return (v + 255) & ~(size_t)255; };
  char* p = (char*)d_ws;
  unsigned short* xb  = (unsigned short*)p; p += alignup((size_t)M * 512 * 2);
  unsigned short* h1b = (unsigned short*)p; p += alignup((size_t)M * 512 * 2);  // blocked
  unsigned short* r1b = (unsigned short*)p; p += alignup((size_t)M * 512 * 2);  // blocked
  unsigned short* w1b = (unsigned short*)p; p += alignup(512 * 512 * 2);
  unsigned short* w2b = (unsigned short*)p; p += alignup(512 * 512 * 2);
  float* dis = (float*)p; p += alignup((size_t)M * 4);
  int* ptr   = (int*)p;   p += alignup((size_t)(M + 1) * 4);
  int* cur   = (int*)p;   p += alignup((size_t)M * 4);
  int* eidx  = (int*)p;   p += alignup((size_t)E * 4);
  int* flag  = (int*)p;   p += alignup(256);
  int* bsum  = (int*)p;   p += alignup(1024);
  int* cnt = (int*)h1b;      // aliases h1b region (dead before GEMM1 writes h1b)
  unsigned short* h2b = xb;  // xb dead after GEMM1 (blocked)

  hipMemsetAsync(cnt, 0, (size_t)M * 4, stream);
  detect64_kernel<<<1, 64, 0, stream>>>(ei, flag);

  prep_kernel<<<2048, 256, 0, stream>>>((const float4*)x, (ushort4*)xb, M * 128,
                                        W1, w1b, W2, w2b);

  const int B = (M + 1023) / 1024;
  count_kernel<<<(E + 255) / 256, 256, 0, stream>>>(ei, flag, cnt, E);
  scan_bsum_kernel<<<B, 1024, 0, stream>>>(cnt, bsum, M);
  scan_boff_kernel<<<1, 64, 0, stream>>>(bsum, ptr + M, B);
  scan_fill_kernel<<<B, 1024, 0, stream>>>(cnt, bsum, ptr, cur, dis, M);
  fill_kernel<<<(E + 255) / 256, 256, 0, stream>>>(ei, flag, cur, eidx, E);

  const int nwg = ((M + 127) / 128) * 4;
  const int nag = ((M + 31) / 32) * 8;
  gemm_kernel<false, true><<<nwg, 256, 0, stream>>>(xb, w1b, dis, h1b, M);
  agg_kernel<false><<<nag, 256, 0, stream>>>(h1b, eidx, ptr, dis, b1, (void*)r1b, M);
  gemm_kernel<true, true><<<nwg, 256, 0, stream>>>(r1b, w2b, dis, h2b, M);
  agg_kernel<true><<<nag, 256, 0, stream>>>(h2b, eidx, ptr, dis, b2, (void*)out, M);
}